// Round 2
// baseline (272.980 us; speedup 1.0000x reference)
//
#include <hip/hip_runtime.h>
#include <math.h>

#define NROWS 8192
#define KDIM  768
#define BM 128
#define BN 128
#define BK 64
#define KTILES (KDIM / BK)   // 12

typedef short bf16x8 __attribute__((ext_vector_type(8)));   // 8 bf16 = 4 VGPRs
typedef float f32x16 __attribute__((ext_vector_type(16)));  // 32x32 accumulator

static __device__ __forceinline__ unsigned short f2bf_rne(float f) {
    unsigned x = __float_as_uint(f);
    unsigned r = x + 0x7fffu + ((x >> 16) & 1u);   // round-to-nearest-even
    return (unsigned short)(r >> 16);
}
// monotonic float<->uint encoding so atomicMax(uint) == float max
static __device__ __forceinline__ unsigned enc_f(float f) {
    unsigned x = __float_as_uint(f);
    return (x & 0x80000000u) ? ~x : (x | 0x80000000u);
}
static __device__ __forceinline__ float dec_f(unsigned u) {
    unsigned x = (u & 0x80000000u) ? (u ^ 0x80000000u) : ~u;
    return __uint_as_float(x);
}

__global__ void init_out_k(unsigned* __restrict__ out) {
    out[blockIdx.x * 256 + threadIdx.x] = enc_f(-INFINITY);
}

// one wave per row: float4 loads, 64-wide shfl reduce, packed ushort4 stores
__global__ __launch_bounds__(256) void normalize_cvt_k(
        const float* __restrict__ ex, const float* __restrict__ ey,
        unsigned short* __restrict__ dst) {
    const int wave = threadIdx.x >> 6, lane = threadIdx.x & 63;
    const int grow = blockIdx.x * 4 + wave;          // 0..16383
    const float* src = (grow < NROWS) ? ex : ey;
    const int row = grow & (NROWS - 1);
    const float4* xr = (const float4*)(src + (size_t)row * KDIM);  // 192 float4
    float4 v[3];
    #pragma unroll
    for (int g = 0; g < 3; ++g) v[g] = xr[lane + g * 64];
    float ss = 0.f;
    #pragma unroll
    for (int g = 0; g < 3; ++g)
        ss += v[g].x * v[g].x + v[g].y * v[g].y + v[g].z * v[g].z + v[g].w * v[g].w;
    #pragma unroll
    for (int off = 32; off > 0; off >>= 1) ss += __shfl_xor(ss, off);
    const float scale = 1.0f / fmaxf(sqrtf(ss), 1e-8f);
    ushort4* dr = (ushort4*)(dst + (size_t)grow * KDIM);   // 192 ushort4
    #pragma unroll
    for (int g = 0; g < 3; ++g) {
        ushort4 o;
        o.x = f2bf_rne(v[g].x * scale); o.y = f2bf_rne(v[g].y * scale);
        o.z = f2bf_rne(v[g].z * scale); o.w = f2bf_rne(v[g].w * scale);
        dr[lane + g * 64] = o;
    }
}

// A = exn bf16 [8192][768] (rows = output rows m)
// B = eyn bf16 [8192][768] (rows = output cols n; sims = A . B^T)
// 128x128 block tile, 4 waves as 2x2, each wave 64x64 = 2x2 tiles of 32x32x16
__global__ __launch_bounds__(256) void gemm_rowmax_k(
        const unsigned short* __restrict__ A,
        const unsigned short* __restrict__ B,
        unsigned* __restrict__ out) {
    // LDS row-major [row][k]: 8 chunks of 8 shorts (16B) per row,
    // chunk slot s holds global chunk g = s ^ (row&7)  (xor swizzle, 0 conflicts R1)
    __shared__ unsigned short As[BM * BK];   // 16 KB
    __shared__ unsigned short Bs[BN * BK];   // 16 KB

    const int tid  = threadIdx.x;
    const int wave = tid >> 6, lane = tid & 63;
    const int br = blockIdx.y, bc = blockIdx.x;

    // ---- staging: per issue one wave covers 8 rows x 128B, lane L -> ldsbase + L*16
    const int srow   = lane >> 3;              // row within chunk-of-8
    const int gchunk = (lane & 7) ^ srow;      // slot (lane&7) holds global chunk gchunk
    const int scol   = gchunk * 8;             // shorts

    const unsigned short* gA[4]; const unsigned short* gB[4];
    unsigned short* lA[4]; unsigned short* lB[4];
    #pragma unroll
    for (int i = 0; i < 4; ++i) {
        int chunk = wave + 4 * i;              // 0..15, 8 rows each
        gA[i] = A + (size_t)(br * BM + chunk * 8 + srow) * KDIM + scol;
        gB[i] = B + (size_t)(bc * BN + chunk * 8 + srow) * KDIM + scol;
        lA[i] = As + chunk * 512;              // 8 rows * 64 shorts
        lB[i] = Bs + chunk * 512;
    }

    // ---- compute geometry
    const int wm = (wave >> 1) * 64, wn = (wave & 1) * 64;
    const int rn = lane & 31, kg = lane >> 5;          // A/B frag: m|n = lane&31, kgroup = lane>>5
    const unsigned short* aBase = As + (wm + rn) * BK;
    const unsigned short* bBase = Bs + (wn + rn) * BK;
    const int rswz = rn & 7;                           // row part of the xor swizzle

    f32x16 acc[2][2] = {};

    for (int kt = 0; kt < KTILES; ++kt) {
        __syncthreads();   // previous tile's reads done before overwrite
        #pragma unroll
        for (int i = 0; i < 4; ++i) {
            __builtin_amdgcn_global_load_lds(
                (const __attribute__((address_space(1))) void*)gA[i],
                (__attribute__((address_space(3))) void*)lA[i], 16, 0, 0);
            __builtin_amdgcn_global_load_lds(
                (const __attribute__((address_space(1))) void*)gB[i],
                (__attribute__((address_space(3))) void*)lB[i], 16, 0, 0);
            gA[i] += BK; gB[i] += BK;
        }
        __syncthreads();   // staging complete

        #pragma unroll
        for (int kk = 0; kk < 4; ++kk) {               // 4 k-steps of 16
            const int slot = (kk * 2 + kg) ^ rswz;     // swizzled 16B chunk
            bf16x8 af[2], bfr[2];
            #pragma unroll
            for (int mi = 0; mi < 2; ++mi)
                af[mi] = *(const bf16x8*)(aBase + mi * 32 * BK + slot * 8);
            #pragma unroll
            for (int ni = 0; ni < 2; ++ni)
                bfr[ni] = *(const bf16x8*)(bBase + ni * 32 * BK + slot * 8);
            #pragma unroll
            for (int mi = 0; mi < 2; ++mi)
                #pragma unroll
                for (int ni = 0; ni < 2; ++ni)
                    acc[mi][ni] = __builtin_amdgcn_mfma_f32_32x32x16_bf16(
                        af[mi], bfr[ni], acc[mi][ni], 0, 0, 0);
        }
    }

    // ---- epilogue: row-max over this wave's 64 columns, then atomic merge
    // C/D 32x32 layout: col = lane&31, row = (reg&3) + 8*(reg>>2) + 4*(lane>>5)
    const int half = lane >> 5;
    #pragma unroll
    for (int mi = 0; mi < 2; ++mi) {
        #pragma unroll
        for (int reg = 0; reg < 16; ++reg) {
            float v = fmaxf(acc[mi][0][reg], acc[mi][1][reg]);
            v = fmaxf(v, __shfl_xor(v, 1));
            v = fmaxf(v, __shfl_xor(v, 2));
            v = fmaxf(v, __shfl_xor(v, 4));
            v = fmaxf(v, __shfl_xor(v, 8));
            v = fmaxf(v, __shfl_xor(v, 16));
            if (rn == 0) {
                int row = br * BM + wm + mi * 32 + (reg & 3) + 8 * (reg >> 2) + 4 * half;
                atomicMax(&out[row], enc_f(v));
            }
        }
    }
}

__global__ void decode_out_k(unsigned* __restrict__ u) {
    int i = blockIdx.x * 256 + threadIdx.x;
    ((float*)u)[i] = dec_f(u[i]);
}

extern "C" void kernel_launch(void* const* d_in, const int* in_sizes, int n_in,
                              void* d_out, int out_size, void* d_ws, size_t ws_size,
                              hipStream_t stream) {
    (void)in_sizes; (void)n_in; (void)out_size; (void)ws_size;
    const float* ex = (const float*)d_in[0];
    const float* ey = (const float*)d_in[1];
    unsigned short* wsb = (unsigned short*)d_ws;     // exn ++ eyn bf16 (25.2 MB)
    unsigned* outu = (unsigned*)d_out;

    init_out_k<<<NROWS / 256, 256, 0, stream>>>(outu);
    normalize_cvt_k<<<(2 * NROWS) / 4, 256, 0, stream>>>(ex, ey, wsb);
    gemm_rowmax_k<<<dim3(NROWS / BN, NROWS / BM), 256, 0, stream>>>(
        wsb, wsb + (size_t)NROWS * KDIM, outu);
    decode_out_k<<<NROWS / 256, 256, 0, stream>>>(outu);
}